// Round 8
// baseline (238.393 us; speedup 1.0000x reference)
//
#include <hip/hip_runtime.h>
#include <math.h>

// Problem constants (fixed by setup_inputs)
constexpr int kB  = 16;
constexpr int kC  = 8;
constexpr int kH  = 512;
constexpr int kW  = 512;
constexpr int kNB = 15;
constexpr int kHW = kH * kW;          // 262144
constexpr int kG  = kHW / 4;          // float4 groups per (b,c) plane = 65536 (pow2)

constexpr int kTiles   = 4;
constexpr int kThreads = (kB * kG) / kTiles;   // 262,144 threads total
constexpr int kBlock   = 256;
constexpr int kGrid    = kThreads / kBlock;    // 1024 blocks

// Bit-exact replica of numpy's universal-intrinsics simd_exp_f32 (Cephes-style,
// Cody-Waite reduction, FMA Horner, final fma(poly, r^2, r+1), 2^q scale).
// Valid for x in [-87, 0] (our range: x = logit - max <= 0, > -40).
__device__ __forceinline__ float np_expf(float x) {
    const float log2e = 1.44269504088896341f;      // 0x3FB8AA3B
    float q = rintf(x * log2e);                    // separate mul, then rint (RNE)
    float r = fmaf(q, -0.693359375f, x);           // Cody-Waite hi
    r = fmaf(q, 2.12194440e-4f, r);                // Cody-Waite lo
    float r2 = r * r;
    float p = fmaf(1.9875691500e-4f, r, 1.3981999507e-3f);
    p = fmaf(p, r, 8.3334519073e-3f);
    p = fmaf(p, r, 4.1665795894e-2f);
    p = fmaf(p, r, 1.6666665459e-1f);
    p = fmaf(p, r, 5.0000001201e-1f);
    p = fmaf(p, r2, r + 1.0f);                     // poly*r^2 + (r + 1)
    return ldexpf(p, (int)q);                      // v_ldexp_f32
}

__device__ __forceinline__ void compute_tile(const float4* l, const float* vf,
                                             float4* o) {
#pragma unroll
    for (int px = 0; px < 4; ++px) {
        float lx[kC];
#pragma unroll
        for (int c = 0; c < kC; ++c)
            lx[c] = reinterpret_cast<const float*>(&l[c])[px];

        // ---- numpy-f32 pipeline replica (binning bit-exact) ----
        float m = lx[0];
#pragma unroll
        for (int c = 1; c < kC; ++c) m = fmaxf(m, lx[c]);

        float e[kC];
#pragma unroll
        for (int c = 0; c < kC; ++c)
            e[c] = np_expf(lx[c] - m);

        // numpy reduces the strided class axis plane-sequentially in f32
        float s = e[0];
#pragma unroll
        for (int c = 1; c < kC; ++c) s = s + e[c];

        // Fast path: p15a = (e * rcp(s)) * 15; within 1e-4 of a boundary (25x
        // margin over the ~4e-6 rcp-path error) redo numpy's exact fl(fl(e/s)*15).
        const float rs = __builtin_amdgcn_rcpf(s);
        int bi[kC];
#pragma unroll
        for (int c = 0; c < kC; ++c) {
            float p15 = (e[c] * rs) * 15.0f;
            if (fabsf(p15 - rintf(p15)) < 1e-4f) {
                p15 = (e[c] / s) * 15.0f;            // exact numpy pipeline
            }
            int bb = (int)p15;                        // trunc == floor (p15 >= 0)
            bi[c] = bb > kNB - 1 ? kNB - 1 : bb;
        }

        // gather + renormalize: continuous, threshold 1.08e-2 -> rcp+mul fine
        float calv[kC];
#pragma unroll
        for (int c = 0; c < kC; ++c)
            calv[c] = vf[c * kNB + bi[c]];
        float csum = calv[0];
#pragma unroll
        for (int c = 1; c < kC; ++c) csum = csum + calv[c];
        const float rcs = __builtin_amdgcn_rcpf(csum);
#pragma unroll
        for (int c = 0; c < kC; ++c)
            reinterpret_cast<float*>(&o[c])[px] = calv[c] * rcs;
    }
}

__global__ __launch_bounds__(kBlock)
void hist_calib_kernel(const float* __restrict__ logits,
                       const float* __restrict__ val_freqs,
                       float* __restrict__ out)
{
    __shared__ float vf[kC * kNB];    // 120 floats
    if (threadIdx.x < kC * kNB) vf[threadIdx.x] = val_freqs[threadIdx.x];
    __syncthreads();

    const int tid = blockIdx.x * kBlock + threadIdx.x;   // 0..262143

    const float4* __restrict__ lg4  = reinterpret_cast<const float4*>(logits);
    float4* __restrict__       out4 = reinterpret_cast<float4*>(out);

    // group index for tile t: g = tid + t*kThreads  (consecutive lanes coalesced)
    // plane address: (b*kC + c)*kG + s4, b = g>>16, s4 = g&65535 (kG = 65536)
    float4 cur[kC], nxt[kC];

    {
        const int g = tid;
        const int b = g >> 16, s4 = g & (kG - 1);
#pragma unroll
        for (int c = 0; c < kC; ++c)
            cur[c] = lg4[(long long)(b * kC + c) * kG + s4];
    }

#pragma unroll
    for (int t = 0; t < kTiles; ++t) {
        // Prefetch next tile BEFORE computing current: HBM latency hides
        // under ~1500 cycles of compute.
        if (t + 1 < kTiles) {
            const int gn = tid + (t + 1) * kThreads;
            const int bn = gn >> 16, s4n = gn & (kG - 1);
#pragma unroll
            for (int c = 0; c < kC; ++c)
                nxt[c] = lg4[(long long)(bn * kC + c) * kG + s4n];
        }

        float4 o[kC];
        compute_tile(cur, vf, o);

        const int g = tid + t * kThreads;
        const int b = g >> 16, s4 = g & (kG - 1);
#pragma unroll
        for (int c = 0; c < kC; ++c)
            out4[(long long)(b * kC + c) * kG + s4] = o[c];

#pragma unroll
        for (int c = 0; c < kC; ++c)
            cur[c] = nxt[c];
    }
}

extern "C" void kernel_launch(void* const* d_in, const int* in_sizes, int n_in,
                              void* d_out, int out_size, void* d_ws, size_t ws_size,
                              hipStream_t stream) {
    const float* logits    = (const float*)d_in[0];
    const float* val_freqs = (const float*)d_in[1];
    float* out = (float*)d_out;

    hist_calib_kernel<<<kGrid, kBlock, 0, stream>>>(logits, val_freqs, out);
}

// Round 9
// 238.383 us; speedup vs baseline: 1.0000x; 1.0000x over previous
//
#include <hip/hip_runtime.h>
#include <math.h>

// Problem constants (fixed by setup_inputs)
constexpr int kB  = 16;
constexpr int kC  = 8;
constexpr int kH  = 512;
constexpr int kW  = 512;
constexpr int kNB = 15;
constexpr int kHW = kH * kW;          // 262144
constexpr int kG  = kHW / 4;          // float4 groups per (b,c) plane = 65536 (pow2)

constexpr int kTiles   = 2;
constexpr int kThreads = (kB * kG) / kTiles;   // 524,288 threads
constexpr int kBlock   = 256;
constexpr int kGrid    = kThreads / kBlock;    // 2048 blocks = 8192 waves = 256 CU x 32

// Bit-exact replica of numpy's universal-intrinsics simd_exp_f32 (Cephes-style,
// Cody-Waite reduction, FMA Horner, final fma(poly, r^2, r+1), 2^q scale).
// Valid for x in [-87, 0] (our range: x = logit - max <= 0, > -40).
__device__ __forceinline__ float np_expf(float x) {
    const float log2e = 1.44269504088896341f;      // 0x3FB8AA3B
    float q = rintf(x * log2e);                    // separate mul, then rint (RNE)
    float r = fmaf(q, -0.693359375f, x);           // Cody-Waite hi
    r = fmaf(q, 2.12194440e-4f, r);                // Cody-Waite lo
    float r2 = r * r;
    float p = fmaf(1.9875691500e-4f, r, 1.3981999507e-3f);
    p = fmaf(p, r, 8.3334519073e-3f);
    p = fmaf(p, r, 4.1665795894e-2f);
    p = fmaf(p, r, 1.6666665459e-1f);
    p = fmaf(p, r, 5.0000001201e-1f);
    p = fmaf(p, r2, r + 1.0f);                     // poly*r^2 + (r + 1)
    return ldexpf(p, (int)q);                      // v_ldexp_f32
}

__device__ __forceinline__ void compute_tile(const float4* l, const float* vf,
                                             float4* o) {
#pragma unroll
    for (int px = 0; px < 4; ++px) {
        float lx[kC];
#pragma unroll
        for (int c = 0; c < kC; ++c)
            lx[c] = reinterpret_cast<const float*>(&l[c])[px];

        // ---- numpy-f32 pipeline replica (binning bit-exact) ----
        float m = lx[0];
#pragma unroll
        for (int c = 1; c < kC; ++c) m = fmaxf(m, lx[c]);

        float e[kC];
#pragma unroll
        for (int c = 0; c < kC; ++c)
            e[c] = np_expf(lx[c] - m);

        // numpy reduces the strided class axis plane-sequentially in f32
        float s = e[0];
#pragma unroll
        for (int c = 1; c < kC; ++c) s = s + e[c];

        // Fast path: p15a = (e * rcp(s)) * 15; within 1e-4 of a boundary (25x
        // margin over the ~4e-6 rcp-path error) redo numpy's exact fl(fl(e/s)*15).
        const float rs = __builtin_amdgcn_rcpf(s);
        int bi[kC];
#pragma unroll
        for (int c = 0; c < kC; ++c) {
            float p15 = (e[c] * rs) * 15.0f;
            if (fabsf(p15 - rintf(p15)) < 1e-4f) {
                p15 = (e[c] / s) * 15.0f;            // exact numpy pipeline
            }
            int bb = (int)p15;                        // trunc == floor (p15 >= 0)
            bi[c] = bb > kNB - 1 ? kNB - 1 : bb;
        }

        // gather + renormalize: continuous, threshold 1.08e-2 -> rcp+mul fine
        float calv[kC];
#pragma unroll
        for (int c = 0; c < kC; ++c)
            calv[c] = vf[c * kNB + bi[c]];
        float csum = calv[0];
#pragma unroll
        for (int c = 1; c < kC; ++c) csum = csum + calv[c];
        const float rcs = __builtin_amdgcn_rcpf(csum);
#pragma unroll
        for (int c = 0; c < kC; ++c)
            reinterpret_cast<float*>(&o[c])[px] = calv[c] * rcs;
    }
}

__global__ __launch_bounds__(kBlock)
void hist_calib_kernel(const float* __restrict__ logits,
                       const float* __restrict__ val_freqs,
                       float* __restrict__ out)
{
    __shared__ float vf[kC * kNB];    // 120 floats
    if (threadIdx.x < kC * kNB) vf[threadIdx.x] = val_freqs[threadIdx.x];
    __syncthreads();

    const int tid = blockIdx.x * kBlock + threadIdx.x;   // 0..524287

    const float4* __restrict__ lg4  = reinterpret_cast<const float4*>(logits);
    float4* __restrict__       out4 = reinterpret_cast<float4*>(out);

    // Tile t handles group g = tid + t*kThreads; b = g>>16, s4 = g&65535.
    const int g0 = tid,            b0 = g0 >> 16, s40 = g0 & (kG - 1);
    const int g1 = tid + kThreads, b1 = g1 >> 16, s41 = g1 & (kG - 1);

    // Issue ALL 16 loads before any compute: 2x memory-level parallelism,
    // and tile 1's DRAM latency hides entirely under tile 0's compute.
    float4 l0[kC], l1[kC];
#pragma unroll
    for (int c = 0; c < kC; ++c)
        l0[c] = lg4[(long long)(b0 * kC + c) * kG + s40];
#pragma unroll
    for (int c = 0; c < kC; ++c)
        l1[c] = lg4[(long long)(b1 * kC + c) * kG + s41];

    float4 o[kC];
    compute_tile(l0, vf, o);
#pragma unroll
    for (int c = 0; c < kC; ++c)
        out4[(long long)(b0 * kC + c) * kG + s40] = o[c];

    compute_tile(l1, vf, o);
#pragma unroll
    for (int c = 0; c < kC; ++c)
        out4[(long long)(b1 * kC + c) * kG + s41] = o[c];
}

extern "C" void kernel_launch(void* const* d_in, const int* in_sizes, int n_in,
                              void* d_out, int out_size, void* d_ws, size_t ws_size,
                              hipStream_t stream) {
    const float* logits    = (const float*)d_in[0];
    const float* val_freqs = (const float*)d_in[1];
    float* out = (float*)d_out;

    hist_calib_kernel<<<kGrid, kBlock, 0, stream>>>(logits, val_freqs, out);
}